// Round 22
// baseline (1296.270 us; speedup 1.0000x reference)
//
#include <hip/hip_runtime.h>

// GPT forward, MI355X. f32 inputs; bf16 MFMA GEMMs with f32 accum;
// LN/softmax/residual kept in f32.
// R22 = R21 + T5 s_setprio(1) around attention's QK^T and PV MFMA clusters
// (m191 regime: multi-block/CU, independent phases -> scheduler can favor
// MFMA-issuing waves). All else byte-identical to R21 (best: 1294.9us).

#define T_SEQ 1024
#define E_DIM 1024
#define H_NUM 16
#define D_HEAD 64
#define L_NUM 6
#define FF_DIM 4096
#define B_NUM 2
#define M_ROWS 2048   // B*T

using bf16x8 = __attribute__((ext_vector_type(8))) __bf16;
using f32x4  = __attribute__((ext_vector_type(4))) float;

__device__ __forceinline__ unsigned short f2bf(float f) {
  unsigned int u = __float_as_uint(f);
  u += 0x7fffu + ((u >> 16) & 1u);   // RNE
  return (unsigned short)(u >> 16);
}

// async global->LDS, 16B per lane. LDS dest is wave-uniform (HW adds lane*16).
__device__ __forceinline__ void gload_lds16(const void* g, void* l) {
  __builtin_amdgcn_global_load_lds(
      (const __attribute__((address_space(1))) unsigned int*)g,
      (__attribute__((address_space(3))) unsigned int*)l, 16, 0, 0);
}

// ---------------- embed ---------------------------------------------------
__global__ __launch_bounds__(256) void embed_k(const int* __restrict__ idx,
                                               const float* __restrict__ tok_w,
                                               const float* __restrict__ pos,
                                               float* __restrict__ x) {
  const int i = blockIdx.x;
  const int t = i & (T_SEQ - 1);
  const int tok = idx[i];
  const float4 a = ((const float4*)(tok_w + (size_t)tok * E_DIM))[threadIdx.x];
  const float4 p = ((const float4*)(pos + (size_t)t * E_DIM))[threadIdx.x];
  float4 o;
  o.x = a.x + p.x; o.y = a.y + p.y; o.z = a.z + p.z; o.w = a.w + p.w;
  ((float4*)(x + (size_t)i * E_DIM))[threadIdx.x] = o;
}

// ------- LN device body: one wave per row, no __syncthreads ---------------
__device__ __forceinline__ void ln_body(const float* __restrict__ x,
                                        const float* __restrict__ s,
                                        const float* __restrict__ b,
                                        unsigned short* __restrict__ out,
                                        int blk) {
  const int wave = threadIdx.x >> 6, lane = threadIdx.x & 63;
  const int row = blk * 4 + wave;
  const float4* xr = (const float4*)(x + (size_t)row * E_DIM);
  float4 v[4];
  float sum = 0.f, sq = 0.f;
  #pragma unroll
  for (int i = 0; i < 4; ++i) {
    v[i] = xr[lane + 64 * i];
    sum += v[i].x + v[i].y + v[i].z + v[i].w;
    sq  += v[i].x * v[i].x + v[i].y * v[i].y + v[i].z * v[i].z + v[i].w * v[i].w;
  }
  #pragma unroll
  for (int off = 1; off < 64; off <<= 1) {
    sum += __shfl_xor(sum, off);
    sq  += __shfl_xor(sq, off);
  }
  const float mean = sum * (1.0f / E_DIM);
  const float var  = sq * (1.0f / E_DIM) - mean * mean;
  const float inv  = 1.0f / sqrtf(var + 1e-5f);
  unsigned short* orow = out + (size_t)row * E_DIM;
  #pragma unroll
  for (int i = 0; i < 4; ++i) {
    const float4 sv = ((const float4*)s)[lane + 64 * i];
    const float4 bv = ((const float4*)b)[lane + 64 * i];
    ushort4 o;
    o.x = f2bf((v[i].x - mean) * inv * sv.x + bv.x);
    o.y = f2bf((v[i].y - mean) * inv * sv.y + bv.y);
    o.z = f2bf((v[i].z - mean) * inv * sv.z + bv.z);
    o.w = f2bf((v[i].w - mean) * inv * sv.w + bv.w);
    *(ushort4*)(orow + 4 * (lane + 64 * i)) = o;
  }
}

// standalone LN (used for LN2)
__global__ __launch_bounds__(256) void ln_k(const float* __restrict__ x,
                                            const float* __restrict__ s,
                                            const float* __restrict__ b,
                                            unsigned short* __restrict__ out) {
  ln_body(x, s, b, out, blockIdx.x);
}

// ------- transpose device body: 32x32 tile, WT[n][k] = bf16(W[k][n]) ------
__device__ __forceinline__ void trans_body(const float* __restrict__ W,
                                           unsigned short* __restrict__ WT,
                                           int K, int N, int b,
                                           float (*tile)[33]) {
  const int nbn = N >> 5;
  const int n0 = (b % nbn) << 5, k0 = (b / nbn) << 5;
  const int tx = threadIdx.x & 31, ty = threadIdx.x >> 5;
  #pragma unroll
  for (int i = ty; i < 32; i += 8)
    tile[i][tx] = W[(size_t)(k0 + i) * N + n0 + tx];
  __syncthreads();
  #pragma unroll
  for (int i = ty; i < 32; i += 8)
    WT[(size_t)(n0 + i) * K + k0 + tx] = f2bf(tile[tx][i]);
}

// ------- fused LN1 + per-layer weight transposes (independent ops) --------
__global__ __launch_bounds__(256) void ln_trans_k(
    const float* __restrict__ x, const float* __restrict__ s,
    const float* __restrict__ b, unsigned short* __restrict__ outh,
    const float* __restrict__ wq, const float* __restrict__ wk,
    const float* __restrict__ wv, const float* __restrict__ wo,
    const float* __restrict__ w1, const float* __restrict__ w2,
    unsigned short* __restrict__ wt_qkv, unsigned short* __restrict__ wt_o,
    unsigned short* __restrict__ wt_f1, unsigned short* __restrict__ wt_f2) {
  __shared__ float tile[32][33];
  const int bid = blockIdx.x;
  if (bid < 512) { ln_body(x, s, b, outh, bid); return; }
  const int tb = bid - 512;
  if (tb < 3072) {
    const int w = tb >> 10;
    const float* W = (w == 0) ? wq : (w == 1) ? wk : wv;
    trans_body(W, wt_qkv + (size_t)w * 1024 * 1024, 1024, 1024, tb & 1023, tile);
  } else if (tb < 4096) {
    trans_body(wo, wt_o, 1024, 1024, tb - 3072, tile);
  } else if (tb < 8192) {
    trans_body(w1, wt_f1, 1024, 4096, tb - 4096, tile);
  } else {
    trans_body(w2, wt_f2, 4096, 1024, tb - 8192, tile);
  }
}

// ------- fused final-LN + head transpose ----------------------------------
__global__ __launch_bounds__(256) void lnf_trans_k(
    const float* __restrict__ x, const float* __restrict__ s,
    const float* __restrict__ b, unsigned short* __restrict__ outh,
    const float* __restrict__ head_w, unsigned short* __restrict__ wth) {
  __shared__ float tile[32][33];
  const int bid = blockIdx.x;
  if (bid < 512) { ln_body(x, s, b, outh, bid); return; }
  trans_body(head_w, wth, 1024, 32000, bid - 512, tile);
}

// -------- layer GEMM: dbuf BK=64, counted vmcnt, 2 raw barriers/K-tile ----
template<int BM, bool RELU, bool BIAS, bool RES, bool OBF16>
__global__ __launch_bounds__(256) void gemm_k(const unsigned short* __restrict__ A,
                                              const unsigned short* __restrict__ WT,
                                              const float* __restrict__ bias,
                                              const float* __restrict__ res,
                                              void* __restrict__ Cout,
                                              int ldc, int K) {
  constexpr int BN = 128;
  constexpr int BK = 64;                    // 128 B rows = 8 slots of 16 B
  constexpr int MF = BM / 32;
  constexpr int AJ = (BM * BK * 2 / 1024) / 4;
  constexpr int BJ = (BN * BK * 2 / 1024) / 4;
  constexpr int NL = AJ + BJ;               // gloads per wave per stage
  __shared__ __align__(16) unsigned short As[2][BM][BK];
  __shared__ __align__(16) unsigned short Bs[2][BN][BK];
  const int tid = threadIdx.x;
  const int row0 = blockIdx.x * BM, col0 = blockIdx.y * BN;
  const int wave = tid >> 6, lane = tid & 63;
  const int wm = (wave >> 1) * (BM / 2), wn = (wave & 1) * 64;
  const int lr = lane & 15, lg = lane >> 4;
  const int ric = lane >> 3, sslot = lane & 7;

  auto stage = [&](int buf, int k0) {
    #pragma unroll
    for (int j = 0; j < AJ; ++j) {
      const int c = wave + 4 * j;
      const int row = c * 8 + ric;
      const int sp = sslot ^ (row & 7);
      gload_lds16(A + (size_t)(row0 + row) * K + k0 + sp * 8,
                  (char*)&As[buf][0][0] + c * 1024);
    }
    #pragma unroll
    for (int j = 0; j < BJ; ++j) {
      const int c = wave + 4 * j;
      const int row = c * 8 + ric;
      const int sp = sslot ^ (row & 7);
      gload_lds16(WT + (size_t)(col0 + row) * K + k0 + sp * 8,
                  (char*)&Bs[buf][0][0] + c * 1024);
    }
  };

  f32x4 acc[MF][4] = {};
  const int nt = K / BK;
  stage(0, 0);
  asm volatile("s_waitcnt vmcnt(0)" ::: "memory");
  __builtin_amdgcn_s_barrier();
  for (int t = 0; t < nt; ++t) {
    const int cur = t & 1;
    if (t + 1 < nt) {
      stage(cur ^ 1, (t + 1) * BK);         // 6 (or 5) loads fly ahead
      asm volatile("s_waitcnt vmcnt(%0)" :: "i"(NL) : "memory");  // drain cur only
    } else {
      asm volatile("s_waitcnt vmcnt(0)" ::: "memory");
    }
    __builtin_amdgcn_s_barrier();           // BAR-1: cur staged block-wide
    #pragma unroll
    for (int ks = 0; ks < 2; ++ks) {
      bf16x8 af[MF], bfr[4];
      #pragma unroll
      for (int m = 0; m < MF; ++m) {
        const int r = wm + m * 16 + lr;
        const int s = (ks * 4 + lg) ^ (r & 7);
        af[m] = *(const bf16x8*)((const char*)&As[cur][0][0] + r * 128 + s * 16);
      }
      #pragma unroll
      for (int n = 0; n < 4; ++n) {
        const int r = wn + n * 16 + lr;
        const int s = (ks * 4 + lg) ^ (r & 7);
        bfr[n] = *(const bf16x8*)((const char*)&Bs[cur][0][0] + r * 128 + s * 16);
      }
      #pragma unroll
      for (int m = 0; m < MF; ++m)
        #pragma unroll
        for (int n = 0; n < 4; ++n)
          acc[m][n] = __builtin_amdgcn_mfma_f32_16x16x32_bf16(af[m], bfr[n], acc[m][n], 0, 0, 0);
    }
    __builtin_amdgcn_s_barrier();           // BAR-2: reads of cur done
  }
  float* Cf = (float*)Cout;
  unsigned short* Cb = (unsigned short*)Cout;
  #pragma unroll
  for (int m = 0; m < MF; ++m) {
    #pragma unroll
    for (int n = 0; n < 4; ++n) {
      const int col = col0 + wn + (n << 4) + lr;
      const float bv = BIAS ? bias[col] : 0.0f;
      #pragma unroll
      for (int r = 0; r < 4; ++r) {
        const int row = row0 + wm + (m << 4) + (lg << 2) + r;
        float val = acc[m][n][r] + bv;
        if (RELU) val = fmaxf(val, 0.0f);
        if (RES)  val += res[(size_t)row * ldc + col];
        if (OBF16) Cb[(size_t)row * ldc + col] = f2bf(val);
        else       Cf[(size_t)row * ldc + col] = val;
      }
    }
  }
}

// ---------------- head GEMM: 256x256, 8 waves, 2 barriers/K-tile ----------
#define LOAD_AF(HALF)                                                         \
  _Pragma("unroll")                                                           \
  for (int mf = 0; mf < 4; ++mf) {                                            \
    const int rr = wm * 64 + mf * 16 + lr;                                    \
    _Pragma("unroll")                                                         \
    for (int ks = 0; ks < 2; ++ks)                                            \
      af[mf][ks] = *(const bf16x8*)&As[buf][HALF][rr]                         \
          [(((ks << 2) + lgp) ^ (rr & 7)) << 3];                              \
  }
#define LOAD_BF(HALF, DST)                                                    \
  _Pragma("unroll")                                                           \
  for (int nf = 0; nf < 2; ++nf) {                                            \
    const int rr = wn * 32 + nf * 16 + lr;                                    \
    _Pragma("unroll")                                                         \
    for (int ks = 0; ks < 2; ++ks)                                            \
      DST[nf][ks] = *(const bf16x8*)&Bs[buf][HALF][rr]                        \
          [(((ks << 2) + lgp) ^ (rr & 7)) << 3];                              \
  }
#define MFMA_Q(MH, NH, BQ)                                                    \
  __builtin_amdgcn_s_setprio(1);                                              \
  _Pragma("unroll")                                                           \
  for (int mf = 0; mf < 4; ++mf)                                              \
    _Pragma("unroll")                                                         \
    for (int nf = 0; nf < 2; ++nf) {                                          \
      acc[MH][NH][mf][nf] = __builtin_amdgcn_mfma_f32_16x16x32_bf16(          \
          af[mf][0], BQ[nf][0], acc[MH][NH][mf][nf], 0, 0, 0);                \
      acc[MH][NH][mf][nf] = __builtin_amdgcn_mfma_f32_16x16x32_bf16(          \
          af[mf][1], BQ[nf][1], acc[MH][NH][mf][nf], 0, 0, 0);                \
    }                                                                         \
  __builtin_amdgcn_s_setprio(0);

__global__ __launch_bounds__(512) void gemm8_k(
    const unsigned short* __restrict__ A, const unsigned short* __restrict__ WT,
    const float* __restrict__ bias, float* __restrict__ C,
    int ldc, int K, int mgrid) {
  constexpr int BK = 64;
  __shared__ __align__(16) unsigned short As[2][2][128][64];
  __shared__ __align__(16) unsigned short Bs[2][2][128][64];
  const int tid = threadIdx.x;
  const int wave = tid >> 6, lane = tid & 63;
  const int wm = wave >> 2, wn = wave & 3;
  const int lr = lane & 15, lgp = lane >> 4;
  const int nwg = gridDim.x;
  const int q = nwg >> 3, r = nwg & 7;
  const int xcd = blockIdx.x & 7;
  const int lgid = (xcd < r ? xcd * (q + 1) : r * (q + 1) + (xcd - r) * q)
                   + (blockIdx.x >> 3);
  const int row0 = (lgid % mgrid) * 256, col0 = (lgid / mgrid) * 256;
  const int srow = lane >> 3, sslot = lane & 7;

  auto stA = [&](int buf, int half, int k0) {
    #pragma unroll
    for (int j = 0; j < 2; ++j) {
      const int row = j * 64 + wave * 8 + srow;
      const int sp = sslot ^ (row & 7);
      gload_lds16(A + (size_t)(row0 + half * 128 + row) * K + k0 + sp * 8,
                  (char*)&As[buf][half][0][0] + j * 8192 + wave * 1024);
    }
  };
  auto stB = [&](int buf, int half, int k0) {
    #pragma unroll
    for (int j = 0; j < 2; ++j) {
      const int row = j * 64 + wave * 8 + srow;
      const int sp = sslot ^ (row & 7);
      gload_lds16(WT + (size_t)(col0 + half * 128 + row) * K + k0 + sp * 8,
                  (char*)&Bs[buf][half][0][0] + j * 8192 + wave * 1024);
    }
  };

  f32x4 acc[2][2][4][2] = {};
  bf16x8 af[4][2], bfq0[2][2], bfq1[2][2];
  const int nt = K / BK;

  stA(0, 0, 0); stB(0, 1, 0); stB(0, 0, 0); stA(0, 1, 0);
  if (nt > 1) {
    stA(1, 0, BK); stB(1, 1, BK);
    asm volatile("s_waitcnt vmcnt(4)" ::: "memory");
  } else {
    asm volatile("s_waitcnt vmcnt(0)" ::: "memory");
  }
  __builtin_amdgcn_s_barrier();

  for (int t = 0; t < nt; ++t) {
    const int buf = t & 1, nbuf = buf ^ 1;
    const int k0 = t * BK;
    // ---- P0: reads buf(A0,B0); stages nbuf(B0,A1); MFMA (0,0)
    LOAD_AF(0)
    LOAD_BF(0, bfq0)
    if (t + 1 < nt) { stB(nbuf, 0, k0 + BK); stA(nbuf, 1, k0 + BK); }
    MFMA_Q(0, 0, bfq0)
    // ---- P1: reads buf(B1); MFMA (0,1)
    LOAD_BF(1, bfq1)
    MFMA_Q(0, 1, bfq1)
    __builtin_amdgcn_s_barrier();   // BAR-A: buf A0/B1 reads done block-wide
    // ---- P2: reads buf(A1); stages buf(A0,t+2); MFMA (1,1)
    LOAD_AF(1)
    if (t + 2 < nt) stA(buf, 0, k0 + 2 * BK);
    MFMA_Q(1, 1, bfq1)
    // ---- P3: stages buf(B1,t+2); MFMA (1,0); counted vmcnt
    if (t + 2 < nt) stB(buf, 1, k0 + 2 * BK);
    MFMA_Q(1, 0, bfq0)
    if (t + 1 < nt) {
      if (t + 2 < nt) asm volatile("s_waitcnt vmcnt(4)" ::: "memory");
      else            asm volatile("s_waitcnt vmcnt(0)" ::: "memory");
    }
    __builtin_amdgcn_s_barrier();   // BAR-B: t+1 staged; buf B0/A1 reads done
  }

  #pragma unroll
  for (int mh = 0; mh < 2; ++mh)
    #pragma unroll
    for (int nh = 0; nh < 2; ++nh)
      #pragma unroll
      for (int mf = 0; mf < 4; ++mf)
        #pragma unroll
        for (int nf = 0; nf < 2; ++nf) {
          const int col = col0 + nh * 128 + wn * 32 + nf * 16 + lr;
          const float bv = bias[col];
          #pragma unroll
          for (int rr = 0; rr < 4; ++rr) {
            const int row = row0 + mh * 128 + wm * 64 + mf * 16 + lgp * 4 + rr;
            C[(size_t)row * ldc + col] = acc[mh][nh][mf][nf][rr] + bv;
          }
        }
}

// ---------------- MFMA flash attention v6: + T5 setprio -------------------
// QBLK=128, K/V dbuf, 1 barrier/tile. K staged via global_load_lds into
// linear XOR-swizzled Ks[2][64][64]; V via regs -> transposed padded Vt.
#define QBLK 128
#define KBLK 64
__global__ __launch_bounds__(512) void fattn_k(const unsigned short* __restrict__ qkv,
                                               unsigned short* __restrict__ ob) {
  const int qt = (T_SEQ / QBLK - 1) - blockIdx.x;   // LPT: big qt first
  const int h = blockIdx.y, b = blockIdx.z;
  const int tid = threadIdx.x;
  const int wave = tid >> 6, lane = tid & 63;       // wave 0..7
  const int lr = lane & 15, lg = lane >> 4;
  const int q0 = qt * QBLK;

  __shared__ __align__(16) unsigned short Qs[QBLK][72];
  __shared__ __align__(16) unsigned short Ks[2][KBLK][64];   // linear, swizzled
  __shared__ __align__(16) unsigned short Vt[2][D_HEAD][72];
  __shared__ __align__(16) unsigned short Ps[QBLK][72];

  const size_t base = (size_t)b * T_SEQ * 3072 + (size_t)h * 64;
  const int srow = tid >> 3, scol = (tid & 7) << 3;  // srow 0..63 (V/Q path)
  const int krow = wave * 8 + (lane >> 3);           // 0..63
  const int ksp  = (lane & 7) ^ (krow & 7);          // inverse-swizzled slot

  uint4 vreg;
  auto stage_k = [&](int buf, int s0) {
    gload_lds16(qkv + base + 1024 + (size_t)(s0 + krow) * 3072 + ksp * 8,
                (char*)&Ks[buf][0][0] + wave * 1024);
  };
  auto load_v = [&](int s0) {
    vreg = *(const uint4*)(qkv + base + 2048 + (size_t)(s0 + srow) * 3072 + scol);
  };
  auto write_v = [&](int buf) {
    const unsigned short* ws = (const unsigned short*)&vreg;
    #pragma unroll
    for (int j = 0; j < 8; ++j) Vt[buf][scol + j][srow] = ws[j];
  };

  // stage Q (128 rows, 2 passes) + first K/V tile into buf 0
  #pragma unroll
  for (int it = 0; it < 2; ++it) {
    const int row = srow + it * 64;
    *(uint4*)&Qs[row][scol] =
        *(const uint4*)(qkv + base + (size_t)(q0 + row) * 3072 + scol);
  }
  stage_k(0, 0);
  load_v(0);
  write_v(0);
  __syncthreads();                     // vmcnt(0)+lgkmcnt(0): tile 0 ready
  bf16x8 qf[2];
  #pragma unroll
  for (int ks = 0; ks < 2; ++ks)
    qf[ks] = *(const bf16x8*)&Qs[wave * 16 + lr][ks * 32 + lg * 8];

  f32x4 acc_o[4] = {};
  float mrow[4], lrow[4];
  #pragma unroll
  for (int r = 0; r < 4; ++r) { mrow[r] = -3.0e38f; lrow[r] = 0.f; }

  const int ntile = 2 * (qt + 1);
  for (int kt = 0; kt < ntile; ++kt) {
    const int s0 = kt * KBLK;
    const int cur = kt & 1;
    f32x4 sacc[4] = {};
    __builtin_amdgcn_s_setprio(1);
    #pragma unroll
    for (int ks = 0; ks < 2; ++ks) {
      #pragma unroll
      for (int nf = 0; nf < 4; ++nf) {
        const int r = nf * 16 + lr;
        bf16x8 kf = *(const bf16x8*)((const char*)&Ks[cur][0][0] +
                                     r * 128 + (((ks << 2) + lg) ^ (r & 7)) * 16);
        sacc[nf] = __builtin_amdgcn_mfma_f32_16x16x32_bf16(qf[ks], kf, sacc[nf], 0, 0, 0);
      }
    }
    __builtin_amdgcn_s_setprio(0);
    // issue next tile's K gload (-> buf^1, unread this tile) + V reg load
    if (kt + 1 < ntile) { stage_k(cur ^ 1, s0 + KBLK); load_v(s0 + KBLK); }
    float sv[4][4];
    #pragma unroll
    for (int nf = 0; nf < 4; ++nf)
      #pragma unroll
      for (int r = 0; r < 4; ++r) sv[nf][r] = sacc[nf][r] * 0.125f;
    if (s0 + KBLK - 1 > q0) {          // diagonal band: mask s > q
      #pragma unroll
      for (int nf = 0; nf < 4; ++nf) {
        const int s = s0 + nf * 16 + lr;
        #pragma unroll
        for (int r = 0; r < 4; ++r) {
          const int qq = q0 + wave * 16 + lg * 4 + r;
          if (s > qq) sv[nf][r] = -3.0e38f;
        }
      }
    }
    float p[4][4];
    #pragma unroll
    for (int r = 0; r < 4; ++r) {
      float mx = fmaxf(fmaxf(sv[0][r], sv[1][r]), fmaxf(sv[2][r], sv[3][r]));
      #pragma unroll
      for (int off = 1; off < 16; off <<= 1) mx = fmaxf(mx, __shfl_xor(mx, off));
      const float mnew = fmaxf(mrow[r], mx);
      const float alpha = __expf(mrow[r] - mnew);
      mrow[r] = mnew;
      float sum = 0.f;
      #pragma unroll
      for (int nf = 0; nf < 4; ++nf) {
        p[nf][r] = __expf(sv[nf][r] - mnew);
        sum += p[nf][r];
      }
      #pragma unroll
      for (int off = 1; off < 16; off <<= 1) sum += __shfl_xor(sum, off);
      lrow[r] = lrow[r] * alpha + sum;
      #pragma unroll
      for (int df = 0; df < 4; ++df) acc_o[df][r] *= alpha;
    }
    // Ps write (wave-private rows; no barrier before PV)
    #pragma unroll
    for (int nf = 0; nf < 4; ++nf)
      #pragma unroll
      for (int r = 0; r < 4; ++r)
        Ps[wave * 16 + lg * 4 + r][nf * 16 + lr] = f2bf(p[nf][r]);
    __builtin_amdgcn_s_setprio(1);
    #pragma unroll
    for (int ks = 0; ks < 2; ++ks) {
      bf16x8 pa = *(const bf16x8*)&Ps[wave * 16 + lr][ks * 32 + lg * 8];
      #pragma unroll
      for (int df = 0; df < 4; ++df) {
        bf16x8 vf = *(const bf16x8*)&Vt[cur][df * 16 + lr][ks * 32 + lg * 8];
        acc_o[df] = __builtin_amdgcn_mfma_f32_16x16x32_bf16(pa, vf, acc_o[df], 0, 0, 0);
      }
    }
    __builtin_amdgcn_s_setprio(0);
    // stage next V into the other buffer (nobody reads it this tile)
    if (kt + 1 < ntile) write_v(cur ^ 1);
    __syncthreads();                   // one barrier per tile (drains gload)
  }
  #pragma unroll
  for (int r = 0; r < 4; ++r) {
    const float inv = 1.0f / lrow[r];
    const int row = q0 + wave * 16 + lg * 4 + r;
    #pragma unroll
    for (int df = 0; df < 4; ++df)
      ob[((size_t)b * T_SEQ + row) * E_DIM + h * 64 + df * 16 + lr] =
          f2bf(acc_o[df][r] * inv);
  }
}

extern "C" void kernel_launch(void* const* d_in, const int* in_sizes, int n_in,
                              void* d_out, int out_size, void* d_ws, size_t ws_size,
                              hipStream_t stream) {
  (void)in_sizes; (void)n_in; (void)out_size; (void)ws_size;
  const int*   idx    = (const int*)d_in[0];
  const float* tok_w  = (const float*)d_in[1];
  const float* pos    = (const float*)d_in[2];
  const float* ln1_s  = (const float*)d_in[3];
  const float* ln1_b  = (const float*)d_in[4];
  const float* wq     = (const float*)d_in[5];
  const float* wk     = (const float*)d_in[6];
  const float* wv     = (const float*)d_in[7];
  const float* wo     = (const float*)d_in[8];
  const float* bo     = (const float*)d_in[9];
  const float* ln2_s  = (const float*)d_in[10];
  const float* ln2_b  = (const float*)d_in[11];
  const float* w1     = (const float*)d_in[12];
  const float* b1     = (const float*)d_in[13];
  const float* w2     = (const float*)d_in[14];
  const float* b2     = (const float*)d_in[15];
  const float* lnf_s  = (const float*)d_in[16];
  const float* lnf_b  = (const float*)d_in[17];
  const float* head_w = (const float*)d_in[18];
  const float* head_b = (const float*)d_in[19];
  float* out = (float*)d_out;

  char* p = (char*)d_ws;
  float* x            = (float*)p;          p += (size_t)M_ROWS * E_DIM * 4;
  unsigned short* qkvb= (unsigned short*)p; p += (size_t)M_ROWS * 3072 * 2;
  unsigned short* h   = (unsigned short*)p; p += (size_t)M_ROWS * E_DIM * 2;
  unsigned short* obuf= (unsigned short*)p; p += (size_t)M_ROWS * E_DIM * 2;
  unsigned short* ff  = (unsigned short*)p; p += (size_t)M_ROWS * FF_DIM * 2;
  unsigned short* wt  = (unsigned short*)p; p += (size_t)3072 * E_DIM * 2;   // qkv
  unsigned short* wto = (unsigned short*)p; p += (size_t)E_DIM * E_DIM * 2;  // wo
  unsigned short* wtf1= (unsigned short*)p; p += (size_t)FF_DIM * E_DIM * 2; // w1
  unsigned short* wtf2= (unsigned short*)p; p += (size_t)E_DIM * FF_DIM * 2; // w2
  unsigned short* wth = (unsigned short*)p; p += (size_t)32000 * E_DIM * 2;  // head

  embed_k<<<M_ROWS, 256, 0, stream>>>(idx, tok_w, pos, x);

  for (int l = 0; l < L_NUM; ++l) {
    const size_t lEE = (size_t)l * E_DIM * E_DIM;
    const size_t lEF = (size_t)l * E_DIM * FF_DIM;
    // ---- fused LN1 + all weight transposes: ONE launch ----
    ln_trans_k<<<12800, 256, 0, stream>>>(
        x, ln1_s + l * E_DIM, ln1_b + l * E_DIM, h,
        wq + lEE, wk + lEE, wv + lEE, wo + lEE, w1 + lEF, w2 + lEF,
        wt, wto, wtf1, wtf2);
    // ---- QKV (fused, N = 3072, bf16 out): BM=64, 768 blocks = 3/CU ----
    gemm_k<64,false,false,false,true><<<dim3(32, 24), 256, 0, stream>>>(
        h, wt, nullptr, nullptr, qkvb, 3072, E_DIM);
    // ---- flash attention v6 ----
    fattn_k<<<dim3(T_SEQ / QBLK, H_NUM, B_NUM), 512, 0, stream>>>(qkvb, obuf);
    // ---- out-proj + bias + residual into x: BM=32, 512 blocks ----
    gemm_k<32,false,true,true,false><<<dim3(64, 8), 256, 0, stream>>>(
        obuf, wto, bo + l * E_DIM, x, x, E_DIM, E_DIM);
    // ---- LN2 ----
    ln_k<<<M_ROWS / 4, 256, 0, stream>>>(x, ln2_s + l * E_DIM, ln2_b + l * E_DIM, h);
    // ---- MLP up + ReLU (bf16 out): BM=64, 1024 blocks = 3/CU ----
    gemm_k<64,true,true,false,true><<<dim3(32, 32), 256, 0, stream>>>(
        h, wtf1, b1 + l * FF_DIM, nullptr, ff, FF_DIM, E_DIM);
    // ---- MLP down + bias + residual into x: BM=32, 512 blocks, K=4096 ----
    gemm_k<32,false,true,true,false><<<dim3(64, 8), 256, 0, stream>>>(
        ff, wtf2, b2 + l * E_DIM, x, x, E_DIM, FF_DIM);
  }

  // ---- fused final LN + head transpose, then 2-barrier 256x256 head ----
  lnf_trans_k<<<32512, 256, 0, stream>>>(x, lnf_s, lnf_b, h, head_w, wth);
  gemm8_k<<<1000, 512, 0, stream>>>(h, wth, head_b, out, 32000, E_DIM, 8);
}

// Round 23
// 1269.034 us; speedup vs baseline: 1.0215x; 1.0215x over previous
//
#include <hip/hip_runtime.h>

// GPT forward, MI355X. f32 inputs; bf16 MFMA GEMMs with f32 accum;
// LN/softmax/residual kept in f32.
// R23 = R22 + MLP-up ported to the head's proven 2-barrier/4-phase
// counted-vmcnt schedule at 128x256 (grid 256 = exactly 1 block/CU,
// per-wave 64x64, MFMA:ds_read 2:1, vmcnt(3) mirror of the head's
// vmcnt(4) hazard graph). Bias+ReLU+bf16-out fused in epilogue.

#define T_SEQ 1024
#define E_DIM 1024
#define H_NUM 16
#define D_HEAD 64
#define L_NUM 6
#define FF_DIM 4096
#define B_NUM 2
#define M_ROWS 2048   // B*T

using bf16x8 = __attribute__((ext_vector_type(8))) __bf16;
using f32x4  = __attribute__((ext_vector_type(4))) float;

__device__ __forceinline__ unsigned short f2bf(float f) {
  unsigned int u = __float_as_uint(f);
  u += 0x7fffu + ((u >> 16) & 1u);   // RNE
  return (unsigned short)(u >> 16);
}

// async global->LDS, 16B per lane. LDS dest is wave-uniform (HW adds lane*16).
__device__ __forceinline__ void gload_lds16(const void* g, void* l) {
  __builtin_amdgcn_global_load_lds(
      (const __attribute__((address_space(1))) unsigned int*)g,
      (__attribute__((address_space(3))) unsigned int*)l, 16, 0, 0);
}

// ---------------- embed ---------------------------------------------------
__global__ __launch_bounds__(256) void embed_k(const int* __restrict__ idx,
                                               const float* __restrict__ tok_w,
                                               const float* __restrict__ pos,
                                               float* __restrict__ x) {
  const int i = blockIdx.x;
  const int t = i & (T_SEQ - 1);
  const int tok = idx[i];
  const float4 a = ((const float4*)(tok_w + (size_t)tok * E_DIM))[threadIdx.x];
  const float4 p = ((const float4*)(pos + (size_t)t * E_DIM))[threadIdx.x];
  float4 o;
  o.x = a.x + p.x; o.y = a.y + p.y; o.z = a.z + p.z; o.w = a.w + p.w;
  ((float4*)(x + (size_t)i * E_DIM))[threadIdx.x] = o;
}

// ------- LN device body: one wave per row, no __syncthreads ---------------
__device__ __forceinline__ void ln_body(const float* __restrict__ x,
                                        const float* __restrict__ s,
                                        const float* __restrict__ b,
                                        unsigned short* __restrict__ out,
                                        int blk) {
  const int wave = threadIdx.x >> 6, lane = threadIdx.x & 63;
  const int row = blk * 4 + wave;
  const float4* xr = (const float4*)(x + (size_t)row * E_DIM);
  float4 v[4];
  float sum = 0.f, sq = 0.f;
  #pragma unroll
  for (int i = 0; i < 4; ++i) {
    v[i] = xr[lane + 64 * i];
    sum += v[i].x + v[i].y + v[i].z + v[i].w;
    sq  += v[i].x * v[i].x + v[i].y * v[i].y + v[i].z * v[i].z + v[i].w * v[i].w;
  }
  #pragma unroll
  for (int off = 1; off < 64; off <<= 1) {
    sum += __shfl_xor(sum, off);
    sq  += __shfl_xor(sq, off);
  }
  const float mean = sum * (1.0f / E_DIM);
  const float var  = sq * (1.0f / E_DIM) - mean * mean;
  const float inv  = 1.0f / sqrtf(var + 1e-5f);
  unsigned short* orow = out + (size_t)row * E_DIM;
  #pragma unroll
  for (int i = 0; i < 4; ++i) {
    const float4 sv = ((const float4*)s)[lane + 64 * i];
    const float4 bv = ((const float4*)b)[lane + 64 * i];
    ushort4 o;
    o.x = f2bf((v[i].x - mean) * inv * sv.x + bv.x);
    o.y = f2bf((v[i].y - mean) * inv * sv.y + bv.y);
    o.z = f2bf((v[i].z - mean) * inv * sv.z + bv.z);
    o.w = f2bf((v[i].w - mean) * inv * sv.w + bv.w);
    *(ushort4*)(orow + 4 * (lane + 64 * i)) = o;
  }
}

// standalone LN (used for LN2)
__global__ __launch_bounds__(256) void ln_k(const float* __restrict__ x,
                                            const float* __restrict__ s,
                                            const float* __restrict__ b,
                                            unsigned short* __restrict__ out) {
  ln_body(x, s, b, out, blockIdx.x);
}

// ------- transpose device body: 32x32 tile, WT[n][k] = bf16(W[k][n]) ------
__device__ __forceinline__ void trans_body(const float* __restrict__ W,
                                           unsigned short* __restrict__ WT,
                                           int K, int N, int b,
                                           float (*tile)[33]) {
  const int nbn = N >> 5;
  const int n0 = (b % nbn) << 5, k0 = (b / nbn) << 5;
  const int tx = threadIdx.x & 31, ty = threadIdx.x >> 5;
  #pragma unroll
  for (int i = ty; i < 32; i += 8)
    tile[i][tx] = W[(size_t)(k0 + i) * N + n0 + tx];
  __syncthreads();
  #pragma unroll
  for (int i = ty; i < 32; i += 8)
    WT[(size_t)(n0 + i) * K + k0 + tx] = f2bf(tile[tx][i]);
}

// ------- fused LN1 + per-layer weight transposes (independent ops) --------
__global__ __launch_bounds__(256) void ln_trans_k(
    const float* __restrict__ x, const float* __restrict__ s,
    const float* __restrict__ b, unsigned short* __restrict__ outh,
    const float* __restrict__ wq, const float* __restrict__ wk,
    const float* __restrict__ wv, const float* __restrict__ wo,
    const float* __restrict__ w1, const float* __restrict__ w2,
    unsigned short* __restrict__ wt_qkv, unsigned short* __restrict__ wt_o,
    unsigned short* __restrict__ wt_f1, unsigned short* __restrict__ wt_f2) {
  __shared__ float tile[32][33];
  const int bid = blockIdx.x;
  if (bid < 512) { ln_body(x, s, b, outh, bid); return; }
  const int tb = bid - 512;
  if (tb < 3072) {
    const int w = tb >> 10;
    const float* W = (w == 0) ? wq : (w == 1) ? wk : wv;
    trans_body(W, wt_qkv + (size_t)w * 1024 * 1024, 1024, 1024, tb & 1023, tile);
  } else if (tb < 4096) {
    trans_body(wo, wt_o, 1024, 1024, tb - 3072, tile);
  } else if (tb < 8192) {
    trans_body(w1, wt_f1, 1024, 4096, tb - 4096, tile);
  } else {
    trans_body(w2, wt_f2, 4096, 1024, tb - 8192, tile);
  }
}

// ------- fused final-LN + head transpose ----------------------------------
__global__ __launch_bounds__(256) void lnf_trans_k(
    const float* __restrict__ x, const float* __restrict__ s,
    const float* __restrict__ b, unsigned short* __restrict__ outh,
    const float* __restrict__ head_w, unsigned short* __restrict__ wth) {
  __shared__ float tile[32][33];
  const int bid = blockIdx.x;
  if (bid < 512) { ln_body(x, s, b, outh, bid); return; }
  trans_body(head_w, wth, 1024, 32000, bid - 512, tile);
}

// -------- layer GEMM: dbuf BK=64, counted vmcnt, 2 raw barriers/K-tile ----
template<int BM, bool RELU, bool BIAS, bool RES, bool OBF16>
__global__ __launch_bounds__(256) void gemm_k(const unsigned short* __restrict__ A,
                                              const unsigned short* __restrict__ WT,
                                              const float* __restrict__ bias,
                                              const float* __restrict__ res,
                                              void* __restrict__ Cout,
                                              int ldc, int K) {
  constexpr int BN = 128;
  constexpr int BK = 64;                    // 128 B rows = 8 slots of 16 B
  constexpr int MF = BM / 32;
  constexpr int AJ = (BM * BK * 2 / 1024) / 4;
  constexpr int BJ = (BN * BK * 2 / 1024) / 4;
  constexpr int NL = AJ + BJ;               // gloads per wave per stage
  __shared__ __align__(16) unsigned short As[2][BM][BK];
  __shared__ __align__(16) unsigned short Bs[2][BN][BK];
  const int tid = threadIdx.x;
  const int row0 = blockIdx.x * BM, col0 = blockIdx.y * BN;
  const int wave = tid >> 6, lane = tid & 63;
  const int wm = (wave >> 1) * (BM / 2), wn = (wave & 1) * 64;
  const int lr = lane & 15, lg = lane >> 4;
  const int ric = lane >> 3, sslot = lane & 7;

  auto stage = [&](int buf, int k0) {
    #pragma unroll
    for (int j = 0; j < AJ; ++j) {
      const int c = wave + 4 * j;
      const int row = c * 8 + ric;
      const int sp = sslot ^ (row & 7);
      gload_lds16(A + (size_t)(row0 + row) * K + k0 + sp * 8,
                  (char*)&As[buf][0][0] + c * 1024);
    }
    #pragma unroll
    for (int j = 0; j < BJ; ++j) {
      const int c = wave + 4 * j;
      const int row = c * 8 + ric;
      const int sp = sslot ^ (row & 7);
      gload_lds16(WT + (size_t)(col0 + row) * K + k0 + sp * 8,
                  (char*)&Bs[buf][0][0] + c * 1024);
    }
  };

  f32x4 acc[MF][4] = {};
  const int nt = K / BK;
  stage(0, 0);
  asm volatile("s_waitcnt vmcnt(0)" ::: "memory");
  __builtin_amdgcn_s_barrier();
  for (int t = 0; t < nt; ++t) {
    const int cur = t & 1;
    if (t + 1 < nt) {
      stage(cur ^ 1, (t + 1) * BK);         // 6 (or 5) loads fly ahead
      asm volatile("s_waitcnt vmcnt(%0)" :: "i"(NL) : "memory");  // drain cur only
    } else {
      asm volatile("s_waitcnt vmcnt(0)" ::: "memory");
    }
    __builtin_amdgcn_s_barrier();           // BAR-1: cur staged block-wide
    #pragma unroll
    for (int ks = 0; ks < 2; ++ks) {
      bf16x8 af[MF], bfr[4];
      #pragma unroll
      for (int m = 0; m < MF; ++m) {
        const int r = wm + m * 16 + lr;
        const int s = (ks * 4 + lg) ^ (r & 7);
        af[m] = *(const bf16x8*)((const char*)&As[cur][0][0] + r * 128 + s * 16);
      }
      #pragma unroll
      for (int n = 0; n < 4; ++n) {
        const int r = wn + n * 16 + lr;
        const int s = (ks * 4 + lg) ^ (r & 7);
        bfr[n] = *(const bf16x8*)((const char*)&Bs[cur][0][0] + r * 128 + s * 16);
      }
      #pragma unroll
      for (int m = 0; m < MF; ++m)
        #pragma unroll
        for (int n = 0; n < 4; ++n)
          acc[m][n] = __builtin_amdgcn_mfma_f32_16x16x32_bf16(af[m], bfr[n], acc[m][n], 0, 0, 0);
    }
    __builtin_amdgcn_s_barrier();           // BAR-2: reads of cur done
  }
  float* Cf = (float*)Cout;
  unsigned short* Cb = (unsigned short*)Cout;
  #pragma unroll
  for (int m = 0; m < MF; ++m) {
    #pragma unroll
    for (int n = 0; n < 4; ++n) {
      const int col = col0 + wn + (n << 4) + lr;
      const float bv = BIAS ? bias[col] : 0.0f;
      #pragma unroll
      for (int r = 0; r < 4; ++r) {
        const int row = row0 + wm + (m << 4) + (lg << 2) + r;
        float val = acc[m][n][r] + bv;
        if (RELU) val = fmaxf(val, 0.0f);
        if (RES)  val += res[(size_t)row * ldc + col];
        if (OBF16) Cb[(size_t)row * ldc + col] = f2bf(val);
        else       Cf[(size_t)row * ldc + col] = val;
      }
    }
  }
}

// ---------------- head GEMM: 256x256, 8 waves, 2 barriers/K-tile ----------
#define LOAD_AF(HALF)                                                         \
  _Pragma("unroll")                                                           \
  for (int mf = 0; mf < 4; ++mf) {                                            \
    const int rr = wm * 64 + mf * 16 + lr;                                    \
    _Pragma("unroll")                                                         \
    for (int ks = 0; ks < 2; ++ks)                                            \
      af[mf][ks] = *(const bf16x8*)&As[buf][HALF][rr]                         \
          [(((ks << 2) + lgp) ^ (rr & 7)) << 3];                              \
  }
#define LOAD_BF(HALF, DST)                                                    \
  _Pragma("unroll")                                                           \
  for (int nf = 0; nf < 2; ++nf) {                                            \
    const int rr = wn * 32 + nf * 16 + lr;                                    \
    _Pragma("unroll")                                                         \
    for (int ks = 0; ks < 2; ++ks)                                            \
      DST[nf][ks] = *(const bf16x8*)&Bs[buf][HALF][rr]                        \
          [(((ks << 2) + lgp) ^ (rr & 7)) << 3];                              \
  }
#define MFMA_Q(MH, NH, BQ)                                                    \
  __builtin_amdgcn_s_setprio(1);                                              \
  _Pragma("unroll")                                                           \
  for (int mf = 0; mf < 4; ++mf)                                              \
    _Pragma("unroll")                                                         \
    for (int nf = 0; nf < 2; ++nf) {                                          \
      acc[MH][NH][mf][nf] = __builtin_amdgcn_mfma_f32_16x16x32_bf16(          \
          af[mf][0], BQ[nf][0], acc[MH][NH][mf][nf], 0, 0, 0);                \
      acc[MH][NH][mf][nf] = __builtin_amdgcn_mfma_f32_16x16x32_bf16(          \
          af[mf][1], BQ[nf][1], acc[MH][NH][mf][nf], 0, 0, 0);                \
    }                                                                         \
  __builtin_amdgcn_s_setprio(0);

__global__ __launch_bounds__(512) void gemm8_k(
    const unsigned short* __restrict__ A, const unsigned short* __restrict__ WT,
    const float* __restrict__ bias, float* __restrict__ C,
    int ldc, int K, int mgrid) {
  constexpr int BK = 64;
  __shared__ __align__(16) unsigned short As[2][2][128][64];
  __shared__ __align__(16) unsigned short Bs[2][2][128][64];
  const int tid = threadIdx.x;
  const int wave = tid >> 6, lane = tid & 63;
  const int wm = wave >> 2, wn = wave & 3;
  const int lr = lane & 15, lgp = lane >> 4;
  const int nwg = gridDim.x;
  const int q = nwg >> 3, r = nwg & 7;
  const int xcd = blockIdx.x & 7;
  const int lgid = (xcd < r ? xcd * (q + 1) : r * (q + 1) + (xcd - r) * q)
                   + (blockIdx.x >> 3);
  const int row0 = (lgid % mgrid) * 256, col0 = (lgid / mgrid) * 256;
  const int srow = lane >> 3, sslot = lane & 7;

  auto stA = [&](int buf, int half, int k0) {
    #pragma unroll
    for (int j = 0; j < 2; ++j) {
      const int row = j * 64 + wave * 8 + srow;
      const int sp = sslot ^ (row & 7);
      gload_lds16(A + (size_t)(row0 + half * 128 + row) * K + k0 + sp * 8,
                  (char*)&As[buf][half][0][0] + j * 8192 + wave * 1024);
    }
  };
  auto stB = [&](int buf, int half, int k0) {
    #pragma unroll
    for (int j = 0; j < 2; ++j) {
      const int row = j * 64 + wave * 8 + srow;
      const int sp = sslot ^ (row & 7);
      gload_lds16(WT + (size_t)(col0 + half * 128 + row) * K + k0 + sp * 8,
                  (char*)&Bs[buf][half][0][0] + j * 8192 + wave * 1024);
    }
  };

  f32x4 acc[2][2][4][2] = {};
  bf16x8 af[4][2], bfq0[2][2], bfq1[2][2];
  const int nt = K / BK;

  stA(0, 0, 0); stB(0, 1, 0); stB(0, 0, 0); stA(0, 1, 0);
  if (nt > 1) {
    stA(1, 0, BK); stB(1, 1, BK);
    asm volatile("s_waitcnt vmcnt(4)" ::: "memory");
  } else {
    asm volatile("s_waitcnt vmcnt(0)" ::: "memory");
  }
  __builtin_amdgcn_s_barrier();

  for (int t = 0; t < nt; ++t) {
    const int buf = t & 1, nbuf = buf ^ 1;
    const int k0 = t * BK;
    // ---- P0: reads buf(A0,B0); stages nbuf(B0,A1); MFMA (0,0)
    LOAD_AF(0)
    LOAD_BF(0, bfq0)
    if (t + 1 < nt) { stB(nbuf, 0, k0 + BK); stA(nbuf, 1, k0 + BK); }
    MFMA_Q(0, 0, bfq0)
    // ---- P1: reads buf(B1); MFMA (0,1)
    LOAD_BF(1, bfq1)
    MFMA_Q(0, 1, bfq1)
    __builtin_amdgcn_s_barrier();   // BAR-A: buf A0/B1 reads done block-wide
    // ---- P2: reads buf(A1); stages buf(A0,t+2); MFMA (1,1)
    LOAD_AF(1)
    if (t + 2 < nt) stA(buf, 0, k0 + 2 * BK);
    MFMA_Q(1, 1, bfq1)
    // ---- P3: stages buf(B1,t+2); MFMA (1,0); counted vmcnt
    if (t + 2 < nt) stB(buf, 1, k0 + 2 * BK);
    MFMA_Q(1, 0, bfq0)
    if (t + 1 < nt) {
      if (t + 2 < nt) asm volatile("s_waitcnt vmcnt(4)" ::: "memory");
      else            asm volatile("s_waitcnt vmcnt(0)" ::: "memory");
    }
    __builtin_amdgcn_s_barrier();   // BAR-B: t+1 staged; buf B0/A1 reads done
  }

  #pragma unroll
  for (int mh = 0; mh < 2; ++mh)
    #pragma unroll
    for (int nh = 0; nh < 2; ++nh)
      #pragma unroll
      for (int mf = 0; mf < 4; ++mf)
        #pragma unroll
        for (int nf = 0; nf < 2; ++nf) {
          const int col = col0 + nh * 128 + wn * 32 + nf * 16 + lr;
          const float bv = bias[col];
          #pragma unroll
          for (int rr = 0; rr < 4; ++rr) {
            const int row = row0 + mh * 128 + wm * 64 + mf * 16 + lgp * 4 + rr;
            C[(size_t)row * ldc + col] = acc[mh][nh][mf][nf][rr] + bv;
          }
        }
}

// ---- MLP-up GEMM: 128x256, 8 waves, 2 barriers/K-tile (head mirror) ------
// A halves = 64 rows; B halves = 128 cols. Per-wave 64x64 (acc[2][2][2][2]).
// stA2 = 1 load/thread, stB2 = 2 -> prologue buf0=6, buf1=3 -> vmcnt(3);
// in-loop P3 vmcnt(3) = P2's A0(t+2) + P3's B1(t+2) outstanding.
#define LOAD_AF2(HALF)                                                        \
  _Pragma("unroll")                                                           \
  for (int mf = 0; mf < 2; ++mf) {                                            \
    const int rr = wm * 32 + mf * 16 + lr;                                    \
    _Pragma("unroll")                                                         \
    for (int ks = 0; ks < 2; ++ks)                                            \
      af[mf][ks] = *(const bf16x8*)&As[buf][HALF][rr]                         \
          [(((ks << 2) + lgp) ^ (rr & 7)) << 3];                              \
  }
#define LOAD_BF2(HALF, DST)                                                   \
  _Pragma("unroll")                                                           \
  for (int nf = 0; nf < 2; ++nf) {                                            \
    const int rr = wn * 32 + nf * 16 + lr;                                    \
    _Pragma("unroll")                                                         \
    for (int ks = 0; ks < 2; ++ks)                                            \
      DST[nf][ks] = *(const bf16x8*)&Bs[buf][HALF][rr]                        \
          [(((ks << 2) + lgp) ^ (rr & 7)) << 3];                              \
  }
#define MFMA_Q2(MH, NH, BQ)                                                   \
  __builtin_amdgcn_s_setprio(1);                                              \
  _Pragma("unroll")                                                           \
  for (int mf = 0; mf < 2; ++mf)                                              \
    _Pragma("unroll")                                                         \
    for (int nf = 0; nf < 2; ++nf) {                                          \
      acc[MH][NH][mf][nf] = __builtin_amdgcn_mfma_f32_16x16x32_bf16(          \
          af[mf][0], BQ[nf][0], acc[MH][NH][mf][nf], 0, 0, 0);                \
      acc[MH][NH][mf][nf] = __builtin_amdgcn_mfma_f32_16x16x32_bf16(          \
          af[mf][1], BQ[nf][1], acc[MH][NH][mf][nf], 0, 0, 0);                \
    }                                                                         \
  __builtin_amdgcn_s_setprio(0);

__global__ __launch_bounds__(512) void gemmup_k(
    const unsigned short* __restrict__ A, const unsigned short* __restrict__ WT,
    const float* __restrict__ bias, unsigned short* __restrict__ C,
    int ldc, int K, int mgrid) {
  constexpr int BK = 64;
  __shared__ __align__(16) unsigned short As[2][2][64][64];    // 32 KB
  __shared__ __align__(16) unsigned short Bs[2][2][128][64];   // 64 KB
  const int tid = threadIdx.x;
  const int wave = tid >> 6, lane = tid & 63;
  const int wm = wave >> 2, wn = wave & 3;
  const int lr = lane & 15, lgp = lane >> 4;
  const int nwg = gridDim.x;
  const int q = nwg >> 3, r = nwg & 7;
  const int xcd = blockIdx.x & 7;
  const int lgid = (xcd < r ? xcd * (q + 1) : r * (q + 1) + (xcd - r) * q)
                   + (blockIdx.x >> 3);
  const int row0 = (lgid % mgrid) * 128, col0 = (lgid / mgrid) * 256;
  const int srow = lane >> 3, sslot = lane & 7;

  auto stA2 = [&](int buf, int half, int k0) {   // 64 rows, 1 load/thread
    const int row = wave * 8 + srow;
    const int sp = sslot ^ (row & 7);
    gload_lds16(A + (size_t)(row0 + half * 64 + row) * K + k0 + sp * 8,
                (char*)&As[buf][half][0][0] + wave * 1024);
  };
  auto stB2 = [&](int buf, int half, int k0) {   // 128 rows, 2 loads/thread
    #pragma unroll
    for (int j = 0; j < 2; ++j) {
      const int row = j * 64 + wave * 8 + srow;
      const int sp = sslot ^ (row & 7);
      gload_lds16(WT + (size_t)(col0 + half * 128 + row) * K + k0 + sp * 8,
                  (char*)&Bs[buf][half][0][0] + j * 8192 + wave * 1024);
    }
  };

  f32x4 acc[2][2][2][2] = {};
  bf16x8 af[2][2], bfq0[2][2], bfq1[2][2];
  const int nt = K / BK;

  stA2(0, 0, 0); stB2(0, 1, 0); stB2(0, 0, 0); stA2(0, 1, 0);   // 6 loads
  if (nt > 1) {
    stA2(1, 0, BK); stB2(1, 1, BK);                             // +3
    asm volatile("s_waitcnt vmcnt(3)" ::: "memory");            // buf0 drained
  } else {
    asm volatile("s_waitcnt vmcnt(0)" ::: "memory");
  }
  __builtin_amdgcn_s_barrier();

  for (int t = 0; t < nt; ++t) {
    const int buf = t & 1, nbuf = buf ^ 1;
    const int k0 = t * BK;
    // ---- P0: reads buf(A0,B0); stages nbuf(B0,A1); MFMA (0,0)
    LOAD_AF2(0)
    LOAD_BF2(0, bfq0)
    if (t + 1 < nt) { stB2(nbuf, 0, k0 + BK); stA2(nbuf, 1, k0 + BK); }
    MFMA_Q2(0, 0, bfq0)
    // ---- P1: reads buf(B1); MFMA (0,1)
    LOAD_BF2(1, bfq1)
    MFMA_Q2(0, 1, bfq1)
    __builtin_amdgcn_s_barrier();   // BAR-A
    // ---- P2: reads buf(A1); stages buf(A0,t+2); MFMA (1,1)
    LOAD_AF2(1)
    if (t + 2 < nt) stA2(buf, 0, k0 + 2 * BK);
    MFMA_Q2(1, 1, bfq1)
    // ---- P3: stages buf(B1,t+2); MFMA (1,0); counted vmcnt
    if (t + 2 < nt) stB2(buf, 1, k0 + 2 * BK);
    MFMA_Q2(1, 0, bfq0)
    if (t + 1 < nt) {
      if (t + 2 < nt) asm volatile("s_waitcnt vmcnt(3)" ::: "memory");
      else            asm volatile("s_waitcnt vmcnt(0)" ::: "memory");
    }
    __builtin_amdgcn_s_barrier();   // BAR-B
  }

  // epilogue: bias + ReLU + bf16 out
  #pragma unroll
  for (int mh = 0; mh < 2; ++mh)
    #pragma unroll
    for (int nh = 0; nh < 2; ++nh)
      #pragma unroll
      for (int mf = 0; mf < 2; ++mf)
        #pragma unroll
        for (int nf = 0; nf < 2; ++nf) {
          const int col = col0 + nh * 128 + wn * 32 + nf * 16 + lr;
          const float bv = bias[col];
          #pragma unroll
          for (int rr = 0; rr < 4; ++rr) {
            const int row = row0 + mh * 64 + wm * 32 + mf * 16 + lgp * 4 + rr;
            C[(size_t)row * ldc + col] =
                f2bf(fmaxf(acc[mh][nh][mf][nf][rr] + bv, 0.0f));
          }
        }
}

// ---------------- MFMA flash attention v6 ---------------------------------
#define QBLK 128
#define KBLK 64
__global__ __launch_bounds__(512) void fattn_k(const unsigned short* __restrict__ qkv,
                                               unsigned short* __restrict__ ob) {
  const int qt = (T_SEQ / QBLK - 1) - blockIdx.x;   // LPT: big qt first
  const int h = blockIdx.y, b = blockIdx.z;
  const int tid = threadIdx.x;
  const int wave = tid >> 6, lane = tid & 63;       // wave 0..7
  const int lr = lane & 15, lg = lane >> 4;
  const int q0 = qt * QBLK;

  __shared__ __align__(16) unsigned short Qs[QBLK][72];
  __shared__ __align__(16) unsigned short Ks[2][KBLK][64];   // linear, swizzled
  __shared__ __align__(16) unsigned short Vt[2][D_HEAD][72];
  __shared__ __align__(16) unsigned short Ps[QBLK][72];

  const size_t base = (size_t)b * T_SEQ * 3072 + (size_t)h * 64;
  const int srow = tid >> 3, scol = (tid & 7) << 3;  // srow 0..63 (V/Q path)
  const int krow = wave * 8 + (lane >> 3);           // 0..63
  const int ksp  = (lane & 7) ^ (krow & 7);          // inverse-swizzled slot

  uint4 vreg;
  auto stage_k = [&](int buf, int s0) {
    gload_lds16(qkv + base + 1024 + (size_t)(s0 + krow) * 3072 + ksp * 8,
                (char*)&Ks[buf][0][0] + wave * 1024);
  };
  auto load_v = [&](int s0) {
    vreg = *(const uint4*)(qkv + base + 2048 + (size_t)(s0 + srow) * 3072 + scol);
  };
  auto write_v = [&](int buf) {
    const unsigned short* ws = (const unsigned short*)&vreg;
    #pragma unroll
    for (int j = 0; j < 8; ++j) Vt[buf][scol + j][srow] = ws[j];
  };

  #pragma unroll
  for (int it = 0; it < 2; ++it) {
    const int row = srow + it * 64;
    *(uint4*)&Qs[row][scol] =
        *(const uint4*)(qkv + base + (size_t)(q0 + row) * 3072 + scol);
  }
  stage_k(0, 0);
  load_v(0);
  write_v(0);
  __syncthreads();
  bf16x8 qf[2];
  #pragma unroll
  for (int ks = 0; ks < 2; ++ks)
    qf[ks] = *(const bf16x8*)&Qs[wave * 16 + lr][ks * 32 + lg * 8];

  f32x4 acc_o[4] = {};
  float mrow[4], lrow[4];
  #pragma unroll
  for (int r = 0; r < 4; ++r) { mrow[r] = -3.0e38f; lrow[r] = 0.f; }

  const int ntile = 2 * (qt + 1);
  for (int kt = 0; kt < ntile; ++kt) {
    const int s0 = kt * KBLK;
    const int cur = kt & 1;
    f32x4 sacc[4] = {};
    __builtin_amdgcn_s_setprio(1);
    #pragma unroll
    for (int ks = 0; ks < 2; ++ks) {
      #pragma unroll
      for (int nf = 0; nf < 4; ++nf) {
        const int r = nf * 16 + lr;
        bf16x8 kf = *(const bf16x8*)((const char*)&Ks[cur][0][0] +
                                     r * 128 + (((ks << 2) + lg) ^ (r & 7)) * 16);
        sacc[nf] = __builtin_amdgcn_mfma_f32_16x16x32_bf16(qf[ks], kf, sacc[nf], 0, 0, 0);
      }
    }
    __builtin_amdgcn_s_setprio(0);
    if (kt + 1 < ntile) { stage_k(cur ^ 1, s0 + KBLK); load_v(s0 + KBLK); }
    float sv[4][4];
    #pragma unroll
    for (int nf = 0; nf < 4; ++nf)
      #pragma unroll
      for (int r = 0; r < 4; ++r) sv[nf][r] = sacc[nf][r] * 0.125f;
    if (s0 + KBLK - 1 > q0) {
      #pragma unroll
      for (int nf = 0; nf < 4; ++nf) {
        const int s = s0 + nf * 16 + lr;
        #pragma unroll
        for (int r = 0; r < 4; ++r) {
          const int qq = q0 + wave * 16 + lg * 4 + r;
          if (s > qq) sv[nf][r] = -3.0e38f;
        }
      }
    }
    float p[4][4];
    #pragma unroll
    for (int r = 0; r < 4; ++r) {
      float mx = fmaxf(fmaxf(sv[0][r], sv[1][r]), fmaxf(sv[2][r], sv[3][r]));
      #pragma unroll
      for (int off = 1; off < 16; off <<= 1) mx = fmaxf(mx, __shfl_xor(mx, off));
      const float mnew = fmaxf(mrow[r], mx);
      const float alpha = __expf(mrow[r] - mnew);
      mrow[r] = mnew;
      float sum = 0.f;
      #pragma unroll
      for (int nf = 0; nf < 4; ++nf) {
        p[nf][r] = __expf(sv[nf][r] - mnew);
        sum += p[nf][r];
      }
      #pragma unroll
      for (int off = 1; off < 16; off <<= 1) sum += __shfl_xor(sum, off);
      lrow[r] = lrow[r] * alpha + sum;
      #pragma unroll
      for (int df = 0; df < 4; ++df) acc_o[df][r] *= alpha;
    }
    #pragma unroll
    for (int nf = 0; nf < 4; ++nf)
      #pragma unroll
      for (int r = 0; r < 4; ++r)
        Ps[wave * 16 + lg * 4 + r][nf * 16 + lr] = f2bf(p[nf][r]);
    __builtin_amdgcn_s_setprio(1);
    #pragma unroll
    for (int ks = 0; ks < 2; ++ks) {
      bf16x8 pa = *(const bf16x8*)&Ps[wave * 16 + lr][ks * 32 + lg * 8];
      #pragma unroll
      for (int df = 0; df < 4; ++df) {
        bf16x8 vf = *(const bf16x8*)&Vt[cur][df * 16 + lr][ks * 32 + lg * 8];
        acc_o[df] = __builtin_amdgcn_mfma_f32_16x16x32_bf16(pa, vf, acc_o[df], 0, 0, 0);
      }
    }
    __builtin_amdgcn_s_setprio(0);
    if (kt + 1 < ntile) write_v(cur ^ 1);
    __syncthreads();
  }
  #pragma unroll
  for (int r = 0; r < 4; ++r) {
    const float inv = 1.0f / lrow[r];
    const int row = q0 + wave * 16 + lg * 4 + r;
    #pragma unroll
    for (int df = 0; df < 4; ++df)
      ob[((size_t)b * T_SEQ + row) * E_DIM + h * 64 + df * 16 + lr] =
          f2bf(acc_o[df][r] * inv);
  }
}

extern "C" void kernel_launch(void* const* d_in, const int* in_sizes, int n_in,
                              void* d_out, int out_size, void* d_ws, size_t ws_size,
                              hipStream_t stream) {
  (void)in_sizes; (void)n_in; (void)out_size; (void)ws_size;
  const int*   idx    = (const int*)d_in[0];
  const float* tok_w  = (const float*)d_in[1];
  const float* pos    = (const float*)d_in[2];
  const float* ln1_s  = (const float*)d_in[3];
  const float* ln1_b  = (const float*)d_in[4];
  const float* wq     = (const float*)d_in[5];
  const float* wk     = (const float*)d_in[6];
  const float* wv     = (const float*)d_in[7];
  const float* wo     = (const float*)d_in[8];
  const float* bo     = (const float*)d_in[9];
  const float* ln2_s  = (const float*)d_in[10];
  const float* ln2_b  = (const float*)d_in[11];
  const float* w1     = (const float*)d_in[12];
  const float* b1     = (const float*)d_in[13];
  const float* w2     = (const float*)d_in[14];
  const float* b2     = (const float*)d_in[15];
  const float* lnf_s  = (const float*)d_in[16];
  const float* lnf_b  = (const float*)d_in[17];
  const float* head_w = (const float*)d_in[18];
  const float* head_b = (const float*)d_in[19];
  float* out = (float*)d_out;

  char* p = (char*)d_ws;
  float* x            = (float*)p;          p += (size_t)M_ROWS * E_DIM * 4;
  unsigned short* qkvb= (unsigned short*)p; p += (size_t)M_ROWS * 3072 * 2;
  unsigned short* h   = (unsigned short*)p; p += (size_t)M_ROWS * E_DIM * 2;
  unsigned short* obuf= (unsigned short*)p; p += (size_t)M_ROWS * E_DIM * 2;
  unsigned short* ff  = (unsigned short*)p; p += (size_t)M_ROWS * FF_DIM * 2;
  unsigned short* wt  = (unsigned short*)p; p += (size_t)3072 * E_DIM * 2;   // qkv
  unsigned short* wto = (unsigned short*)p; p += (size_t)E_DIM * E_DIM * 2;  // wo
  unsigned short* wtf1= (unsigned short*)p; p += (size_t)FF_DIM * E_DIM * 2; // w1
  unsigned short* wtf2= (unsigned short*)p; p += (size_t)E_DIM * FF_DIM * 2; // w2
  unsigned short* wth = (unsigned short*)p; p += (size_t)32000 * E_DIM * 2;  // head

  embed_k<<<M_ROWS, 256, 0, stream>>>(idx, tok_w, pos, x);

  for (int l = 0; l < L_NUM; ++l) {
    const size_t lEE = (size_t)l * E_DIM * E_DIM;
    const size_t lEF = (size_t)l * E_DIM * FF_DIM;
    // ---- fused LN1 + all weight transposes: ONE launch ----
    ln_trans_k<<<12800, 256, 0, stream>>>(
        x, ln1_s + l * E_DIM, ln1_b + l * E_DIM, h,
        wq + lEE, wk + lEE, wv + lEE, wo + lEE, w1 + lEF, w2 + lEF,
        wt, wto, wtf1, wtf2);
    // ---- QKV (fused, N = 3072, bf16 out): BM=64, 768 blocks = 3/CU ----
    gemm_k<64,false,false,false,true><<<dim3(32, 24), 256, 0, stream>>>(
        h, wt, nullptr, nullptr, qkvb, 3072, E_DIM);
    // ---- flash attention v6 ----
    fattn_k<<<dim3(T_SEQ / QBLK, H_NUM, B_NUM), 512, 0, stream>>>(qkvb, obuf);
    // ---- out-proj + bias + residual into x: BM=32, 512 blocks ----
    gemm_k<32,false,true,true,false><<<dim3(64, 8), 256, 0, stream>>>(
        obuf, wto, bo + l * E_DIM, x, x, E_DIM, E_DIM);
    // ---- LN2 ----
    ln_k<<<M_ROWS / 4, 256, 0, stream>>>(x, ln2_s + l * E_DIM, ln2_b + l * E_DIM, h);
    // ---- MLP up + ReLU (bf16 out): 128x256 head-mirror, 256 blocks ----
    gemmup_k<<<256, 512, 0, stream>>>(
        h, wtf1, b1 + l * FF_DIM, ff, FF_DIM, E_DIM, 16);
    // ---- MLP down + bias + residual into x: BM=32, 512 blocks, K=4096 ----
    gemm_k<32,false,true,true,false><<<dim3(64, 8), 256, 0, stream>>>(
        ff, wtf2, b2 + l * E_DIM, x, x, E_DIM, FF_DIM);
  }

  // ---- fused final LN + head transpose, then 2-barrier 256x256 head ----
  lnf_trans_k<<<32512, 256, 0, stream>>>(x, lnf_s, lnf_b, h, head_w, wth);
  gemm8_k<<<1000, 512, 0, stream>>>(h, wth, head_b, out, 32000, E_DIM, 8);
}